// Round 5
// baseline (159.187 us; speedup 1.0000x reference)
//
#include <hip/hip_runtime.h>
#include <stdint.h>

// Problem constants (reference: B=2, C=4, SPATIAL=(128,128,128), N_PTS=32, THR=0.5)
#define Bn 2
#define Cn 4
#define Sn (128 * 128 * 128)   // 2^21 voxels per (b,c)
#define NPTS 32
#define NBINS 1025             // probs in (0.5, 1] -> one binade; (bits-0x3F000000)>>13 in [0,1024]
#define THRf 0.5f
#define PB 4096                // voxels per block in the fused pass
#define BT 512                 // threads/block: 8 waves; 4 blk/CU -> grid exactly co-resident
#define FB 1024                // single-class survivor cap in the selection epilogue (expected ~80)
#define INIT_MAGIC 0x5A17F00Du // self-init flag value (non-repeating bytes: != any byte-poison)

__device__ __forceinline__ int bin_of_bits(unsigned int u) {
    return (int)((u - 0x3F000000u) >> 13);
}

// Softmax over the 4 classes at one voxel; mirrors jax.nn.softmax exactly
// (exp(x-max)/sum, sequential sum c=0..3). Only the argmax class can exceed 0.5.
// DO NOT re-associate: bit-exactness with the jax reference is load-bearing.
__device__ __forceinline__ void softmax_argmax4(float l0, float l1, float l2, float l3,
                                                int* cm_out, float* p_out) {
    float m = fmaxf(fmaxf(l0, l1), fmaxf(l2, l3));
    float e0 = expf(l0 - m);
    float e1 = expf(l1 - m);
    float e2 = expf(l2 - m);
    float e3 = expf(l3 - m);
    float s = ((e0 + e1) + e2) + e3;
    float em = e0; int cm = 0;
    if (e1 > em) { em = e1; cm = 1; }
    if (e2 > em) { em = e2; cm = 2; }
    if (e3 > em) { em = e3; cm = 3; }
    *cm_out = cm;
    *p_out = em / s;
}

// Single fused kernel. Lessons ledger:
// R9:  per-block __threadfence = buffer_wbl2 storm (345us). -> sc1 stores for cand,
//      release via barrier vmcnt-drain before the done RMW; acquire fence only in
//      consumer blocks.
// R10: 2-block epilogue re-read cand TWICE with dependent L2-cold loads -> 88us
//      tail. -> phase 2.5 publishes the candidate histogram (gh) during streaming.
// R11: tail still ~49us (1 block/batch + guarded loads). -> last-4-finishers
//      select one class each; branch-free 8-deep load batches. Tail now ~5us.
// R12 (this round): VALUBusy x dur is constant (~12.4us) across R2/R3/R4 ->
//      streaming wall ~55us is dependency-starved, NOT BW/VALU-bound. Smoking gun:
//      VGPR_Count=20 (compiler serialized everything; 64 available at 8 waves/EU).
//      -> hoist all 8 float4 loads up front + __launch_bounds__(BT,8) for ILP;
//      -> self-init gh/cnt/done via MAGIC flag (drops the host memset dispatch).
__global__ __launch_bounds__(BT, 8) void fused_kernel(const float* __restrict__ logits,
                                                      unsigned int* __restrict__ cnt,
                                                      unsigned int* __restrict__ gh,
                                                      uint2* __restrict__ cand,
                                                      int cap,
                                                      unsigned int* __restrict__ done,
                                                      unsigned int* __restrict__ done2,
                                                      unsigned int* __restrict__ iflag,
                                                      unsigned int* __restrict__ validn,
                                                      uint2* __restrict__ topk,
                                                      int* __restrict__ out) {
    __shared__ unsigned int lh[Cn * NBINS];   // 16.4 KB: per-class radix hist
    __shared__ unsigned int lcut[Cn], cls_cnt[Cn], cls_base[Cn], cls_pos[Cn];
    __shared__ unsigned int s_old;
    // epilogue-only: single-class survivor buffer + scalars
    __shared__ uint2 fbuf[FB];                // 8.2 KB
    __shared__ unsigned int s_T, s_m;
    __shared__ int pre[Cn + 1];

    const int b = blockIdx.y;
    const int t = threadIdx.x;
    const int lane = t & 63;

    // phase 1a: issue ALL 8 float4 loads up front (128 B/thread in flight).
    const float* base = logits + (size_t)b * Cn * Sn;
    const float4* s0 = (const float4*)base;
    const float4* s1 = (const float4*)(base + Sn);
    const float4* s2 = (const float4*)(base + 2 * Sn);
    const float4* s3 = (const float4*)(base + 3 * Sn);
    const int qs = blockIdx.x * (PB / 4);
    const int q0 = qs + t;
    const int q1 = qs + BT + t;
    float4 u0 = s0[q0], u1 = s1[q0], u2 = s2[q0], u3 = s3[q0];
    float4 w0 = s0[q1], w1 = s1[q1], w2 = s2[q1], w3 = s3[q1];

    // self-init (replaces the host memset): block x==0 of each batch zeroes its
    // batch's global counters with sc1 stores, then publishes MAGIC. Other blocks
    // check the flag only at phase 2.5 (long after it is set -> no real spin).
    if (blockIdx.x == 0) {
        unsigned int* gz = gh + (size_t)b * Cn * NBINS;
        for (int j = t; j < Cn * NBINS; j += BT)
            __hip_atomic_store(&gz[j], 0u, __ATOMIC_RELAXED, __HIP_MEMORY_SCOPE_AGENT);
        if (t < Cn)
            __hip_atomic_store(&cnt[b * Cn + t], 0u, __ATOMIC_RELAXED, __HIP_MEMORY_SCOPE_AGENT);
        if (t == Cn)
            __hip_atomic_store(&done[b], 0u, __ATOMIC_RELAXED, __HIP_MEMORY_SCOPE_AGENT);
        if (t == Cn + 1)
            __hip_atomic_store(&done2[b], 0u, __ATOMIC_RELAXED, __HIP_MEMORY_SCOPE_AGENT);
        __syncthreads();   // drain vmcnt: zeroes reach the coherence point
        if (t == 0)
            __hip_atomic_store(&iflag[b], INIT_MAGIC, __ATOMIC_RELAXED, __HIP_MEMORY_SCOPE_AGENT);
    }

    // LDS hist init (overlaps the in-flight global loads)
    for (int j = t; j < Cn * NBINS; j += BT) lh[j] = 0u;
    if (t < Cn) { lcut[t] = 0u; cls_cnt[t] = 0u; cls_pos[t] = 0u; }
    __syncthreads();

    // phase 1b: softmax both voxel groups; results stay in registers
    unsigned int pk[PB / BT];   // 8 packed results per thread
    #define PROC4(V0, V1, V2, V3, IT) do {                                        \
        const float* a0 = &V0.x; const float* a1 = &V1.x;                         \
        const float* a2 = &V2.x; const float* a3 = &V3.x;                         \
        _Pragma("unroll")                                                         \
        for (int k = 0; k < 4; ++k) {                                             \
            int cm; float p;                                                      \
            softmax_argmax4(a0[k], a1[k], a2[k], a3[k], &cm, &p);                 \
            unsigned int pv = 0u;                                                 \
            if (p > THRf) {                                                       \
                unsigned int off = __float_as_uint(p) - 0x3F000000u;              \
                atomicAdd(&lh[cm * NBINS + (int)(off >> 13)], 1u);                \
                pv = (off << 2) | (unsigned int)cm;                               \
            }                                                                     \
            pk[(IT) * 4 + k] = pv;                                                \
        }                                                                         \
    } while (0)
    PROC4(u0, u1, u2, u3, 0);
    PROC4(w0, w1, w2, w3, 1);
    #undef PROC4
    __syncthreads();

    // phase 2: wave w (w<4) computes local cutoff for class w (64 lanes x 17 bins).
    // Entries below the local cutoff have >=32 strictly-greater local entries ->
    // global rank >= 32 -> safe to drop. Union over blocks is a superset of top-32.
    {
        const int wave = t >> 6;
        if (wave < Cn) {
            const unsigned int* h = &lh[wave * NBINS];
            const int lo = lane * 17;
            unsigned int cs = 0;
            #pragma unroll
            for (int k = 0; k < 17; ++k) {
                int bin = lo + k;
                if (bin < NBINS) cs += h[bin];
            }
            unsigned int S = cs;  // inclusive suffix sum over lanes [lane..63]
            #pragma unroll
            for (int off = 1; off < 64; off <<= 1) {
                unsigned int v = __shfl_down(S, off, 64);
                if (lane + off < 64) S += v;
            }
            unsigned int suf = S - cs;
            if (S >= NPTS && suf < NPTS) {   // exactly one lane (when total >= 32)
                unsigned int acc = suf;
                int hi = min(lo + 16, NBINS - 1);
                for (int bin = hi; bin >= lo; --bin) {
                    acc += h[bin];
                    if (acc >= NPTS) {
                        lcut[wave] = (unsigned int)bin;
                        cls_cnt[wave] = acc;
                        break;
                    }
                }
            }
            if (lane == 0 && S < NPTS) cls_cnt[wave] = S;  // total<32: lcut=0, emit all
        }
    }
    __syncthreads();

    // gate: global counters must be zeroed before any gh/cnt/done use. The flag
    // was set ~the whole streaming phase ago; this poll never actually iterates.
    if (t == 0) {
        while (__hip_atomic_load(&iflag[b], __ATOMIC_RELAXED, __HIP_MEMORY_SCOPE_AGENT)
               != INIT_MAGIC)
            __builtin_amdgcn_s_sleep(2);
    }
    __syncthreads();

    // phase 2.5: publish surviving bins (bin >= lcut, nonzero) into the global
    // per-(b,c) histogram == exactly the histogram of all emitted candidates.
    // Fire-and-forget device-scope atomics, ~35 per class per block.
    {
        const int wave = t >> 6;
        if (wave < Cn) {
            const unsigned int* h = &lh[wave * NBINS];
            unsigned int* g = gh + (size_t)(b * Cn + wave) * NBINS;
            for (int bin = (int)lcut[wave] + lane; bin < NBINS; bin += 64) {
                unsigned int v = h[bin];
                if (v) atomicAdd(&g[bin], v);
            }
        }
    }
    // reservation: one global atomic per (block, class) (device-scope sc1 RMW)
    if (t < Cn && cls_cnt[t] > 0)
        cls_base[t] = atomicAdd(&cnt[b * Cn + t], cls_cnt[t]);
    __syncthreads();

    // phase 3: emit survivors straight from registers (~130/block total).
    // Device-scope relaxed atomic stores (sc0 sc1): visible at the coherence point
    // once each wave's vmcnt drains -> no per-block release fence needed.
    #pragma unroll
    for (int j = 0; j < PB / BT; ++j) {
        unsigned int pv = pk[j];
        if (pv != 0u) {
            unsigned int cm = pv & 3u;
            if ((pv >> 15) >= lcut[cm]) {   // pv>>15 == p_off>>13 == bin
                unsigned int pos = cls_base[cm] + atomicAdd(&cls_pos[cm], 1u);
                if (pos < (unsigned int)cap) {
                    int it = j >> 2, k = j & 3;
                    unsigned int idx = (unsigned int)((qs + it * BT + t) * 4 + k);
                    unsigned long long packed =
                        ((unsigned long long)idx << 32) | (0x3F000000u + (pv >> 2));
                    __hip_atomic_store(
                        (unsigned long long*)&cand[(size_t)(b * Cn + cm) * cap + pos],
                        packed, __ATOMIC_RELAXED, __HIP_MEMORY_SCOPE_AGENT);
                }
            }
        }
    }

    // ---- epilogue: last FOUR finishers of this batch each select ONE class ----
    // __syncthreads() drains every wave's vmcnt (sc1 stores + gh/cnt atomics reach
    // the coherence point) before t==0 issues the done RMW -> release w/o wbl2.
    __syncthreads();
    if (t == 0) s_old = atomicAdd(&done[b], 1u);
    __syncthreads();
    const unsigned int NX = gridDim.x;
    if (s_old + 4u < NX) return;              // keep the last 4 increments
    const int csel = (int)(NX - 1u - s_old);  // unique in 0..3
    // spin until every block of this batch has released its results; we wait on
    // <=3 stragglers, all schedulable (>=NX-4 slots already freed) -> no deadlock.
    if (t == 0) {
        while (__hip_atomic_load(&done[b], __ATOMIC_RELAXED, __HIP_MEMORY_SCOPE_AGENT) < NX)
            __builtin_amdgcn_s_sleep(2);
    }
    __syncthreads();
    __threadfence();   // acquire (buffer_inv): 8 blocks device-wide pay this

    const int bc = b * Cn + csel;
    // load this class's global histogram (complete) into lh[0..NBINS)
    for (int j = t; j < NBINS; j += BT) lh[j] = gh[(size_t)bc * NBINS + j];
    if (t == 0) { s_T = 0u; s_m = 0u; }
    __syncthreads();
    const int n = min((int)cnt[bc], cap);

    // exact global cutoff: wave 0 scans the 1025 bins
    if (t < 64) {
        const int lo = lane * 17;
        unsigned int cs = 0;
        #pragma unroll
        for (int k = 0; k < 17; ++k) {
            int bin = lo + k;
            if (bin < NBINS) cs += lh[bin];
        }
        unsigned int S = cs;
        #pragma unroll
        for (int off = 1; off < 64; off <<= 1) {
            unsigned int v = __shfl_down(S, off, 64);
            if (lane + off < 64) S += v;
        }
        unsigned int suf = S - cs;
        if (S >= NPTS && suf < NPTS) {
            unsigned int acc = suf;
            int hi = min(lo + 16, NBINS - 1);
            for (int bin = hi; bin >= lo; --bin) {
                acc += lh[bin];
                if (acc >= NPTS) { s_T = (unsigned int)bin; break; }
            }
        }
        // S < NPTS: s_T stays 0 -> keep everything
    }
    __syncthreads();
    const unsigned int T = s_T;

    // single filtered pass, branch-free 8-deep load batches (true MLP)
    {
        const uint2* src = cand + (size_t)bc * cap;
        for (int j0 = t; j0 < n; j0 += BT * 8) {
            uint2 e[8];
            #pragma unroll
            for (int k = 0; k < 8; ++k) {
                int j = j0 + k * BT;
                e[k] = src[j < n ? j : (n - 1)];   // clamped: load always issues
            }
            #pragma unroll
            for (int k = 0; k < 8; ++k) {
                int j = j0 + k * BT;
                if (j < n && (unsigned int)bin_of_bits(e[k].x) >= T) {
                    unsigned int pos = atomicAdd(&s_m, 1u);
                    if (pos < FB) fbuf[pos] = e[k];
                }
            }
        }
    }
    __syncthreads();

    // exact rank with jax tie-break (higher prob first; equal prob -> lower idx
    // first); ranks are distinct (idx unique per class). ~80 survivors, 1 pass.
    const int m = min((int)s_m, FB);
    const int vn = min(n, NPTS);
    if (t == 0)
        __hip_atomic_store(&validn[bc], (unsigned int)vn,
                           __ATOMIC_RELAXED, __HIP_MEMORY_SCOPE_AGENT);
    for (int i = t; i < m; i += BT) {
        uint2 e = fbuf[i];
        int rank = 0;
        for (int j = 0; j < m; ++j) {
            uint2 o = fbuf[j];
            rank += (int)((o.x > e.x) || (o.x == e.x && o.y < e.y));
        }
        if (rank < vn) {
            unsigned long long packed = ((unsigned long long)e.y << 32) | e.x;
            __hip_atomic_store((unsigned long long*)&topk[bc * NPTS + rank],
                               packed, __ATOMIC_RELAXED, __HIP_MEMORY_SCOPE_AGENT);
        }
    }

    // ---- final emit: last class-finisher of this batch writes the 128 slots ----
    __syncthreads();   // drain sc1 topk/validn stores before done2 RMW (release)
    if (t == 0) s_old = atomicAdd(&done2[b], 1u);
    __syncthreads();
    if (s_old != 3u) return;
    __threadfence();   // acquire: see the other 3 classes' topk/validn

    if (t == 0) {
        int acc = 0;
        for (int oc = 0; oc < Cn; ++oc) {
            pre[oc] = acc;
            acc += (int)validn[b * Cn + ((oc + 1) & 3)];   // class order [1,2,3,0]
        }
        pre[Cn] = acc;
    }
    __syncthreads();

    if (t < Cn * NPTS) {
        const int j = t;
        int label = -1, z = 0, y = 0, x = 0;
        if (j < pre[Cn]) {
            int oc = 0;
            while (j >= pre[oc + 1]) ++oc;
            int c = (oc + 1) & 3;
            int r = j - pre[oc];
            uint2 e = topk[(b * Cn + c) * NPTS + r];
            int idx = (int)e.y;
            z = idx >> 14;          // idx / (128*128)
            y = (idx >> 7) & 127;   // (idx / 128) % 128
            x = idx & 127;          // idx % 128
            label = c;
        }
        int* coords = out;                       // 2*128*3 = 768 ints
        int* labels = out + Bn * Cn * NPTS * 3;  // then 2*128 = 256 ints
        int bo = b * Cn * NPTS + j;
        coords[bo * 3 + 0] = z;
        coords[bo * 3 + 1] = y;
        coords[bo * 3 + 2] = x;
        labels[bo] = label;
    }
    // reset the init flag so a skipped harness poison can never leave stale MAGIC
    __syncthreads();
    if (t == 0)
        __hip_atomic_store(&iflag[b], 0u, __ATOMIC_RELAXED, __HIP_MEMORY_SCOPE_AGENT);
}

extern "C" void kernel_launch(void* const* d_in, const int* in_sizes, int n_in,
                              void* d_out, int out_size, void* d_ws, size_t ws_size,
                              hipStream_t stream) {
    const float* logits = (const float*)d_in[0];
    int* out = (int*)d_out;

    // Workspace layout (all counters self-initialized on device; no host memset)
    unsigned int* cnt = (unsigned int*)d_ws;             // 8 u32   @0
    unsigned int* done = cnt + Bn * Cn;                  // 2 u32   @32
    unsigned int* done2 = done + Bn;                     // 2 u32   @40
    unsigned int* iflag = done2 + Bn;                    // 2 u32   @48
    unsigned int* gh = iflag + Bn;                       // 8*1025  @56
    unsigned int* validn = gh + Bn * Cn * NBINS;         // 8 u32
    uint2* topk = (uint2*)(validn + Bn * Cn + 2);        // 256 uint2 (8B-aligned: +2 pads to @32904)
    uint2* cand = topk + Bn * Cn * NPTS;
    size_t fixed = (size_t)((char*)cand - (char*)d_ws);
    int cap = (int)((ws_size - fixed) / (Bn * Cn * sizeof(uint2)));
    if (cap > (1 << 18)) cap = 1 << 18;   // 256k entries/bc >> the ~18k expected
    if (cap < 4096) cap = 4096;

    dim3 grid(Sn / PB, Bn);   // (512, 2) = 1024 blocks, exactly co-resident at 4 blk/CU
    fused_kernel<<<grid, BT, 0, stream>>>(logits, cnt, gh, cand, cap,
                                          done, done2, iflag, validn, topk, out);
}

// Round 6
// 117.790 us; speedup vs baseline: 1.3514x; 1.3514x over previous
//
#include <hip/hip_runtime.h>
#include <stdint.h>

// Problem constants (reference: B=2, C=4, SPATIAL=(128,128,128), N_PTS=32, THR=0.5)
#define Bn 2
#define Cn 4
#define Sn (128 * 128 * 128)   // 2^21 voxels per (b,c)
#define NPTS 32
#define NBINS 1025             // probs in (0.5, 1] -> one binade; (bits-0x3F000000)>>13 in [0,1024]
#define THRf 0.5f
#define PB 4096                // voxels per block in the streaming pass
#define BT 512                 // streaming threads/block: 8 waves
#define BT2 1024               // select threads/block
#define FB 1024                // per-class survivor cap in select (expected m ~ 80)

__device__ __forceinline__ int bin_of_bits(unsigned int u) {
    return (int)((u - 0x3F000000u) >> 13);
}

// Softmax over the 4 classes at one voxel; mirrors jax.nn.softmax exactly
// (exp(x-max)/sum, sequential sum c=0..3). Only the argmax class can exceed 0.5.
// DO NOT re-associate: bit-exactness with the jax reference is load-bearing.
__device__ __forceinline__ void softmax_argmax4(float l0, float l1, float l2, float l3,
                                                int* cm_out, float* p_out) {
    float m = fmaxf(fmaxf(l0, l1), fmaxf(l2, l3));
    float e0 = expf(l0 - m);
    float e1 = expf(l1 - m);
    float e2 = expf(l2 - m);
    float e3 = expf(l3 - m);
    float s = ((e0 + e1) + e2) + e3;
    float em = e0; int cm = 0;
    if (e1 > em) { em = e1; cm = 1; }
    if (e2 > em) { em = e2; cm = 2; }
    if (e3 > em) { em = e3; cm = 3; }
    *cm_out = cm;
    *p_out = em / s;
}

// Lessons ledger (measured on MI355X):
// R9:  per-block __threadfence in a 1024-block kernel = buffer_wbl2 storm (345us).
// R10: 2-block epilogue with dependent L2-cold loads = 88us tail.
// R11: 4x-parallel epilogue + branch-free 8-deep loads -> tail ~5us.
// R12: load-hoist + __launch_bounds__(BT,8) + self-init gate REGRESSED 60->92us
//      (compiler re-sunk the loads; VGPR still 24; added ~32us stall). Reverted.
// R13 (this round): the fusion experiment is CONCLUDED NEGATIVE. R0's two-kernel
//      structure ran every kernel <41us (all top-5 dispatches were the harness's
//      41us poison fills) and is still the best total (120us). In-dispatch
//      cross-block coherence (sc1 stores + spins + fences) costs more than the
//      second launch. This version: two dispatches; streaming kernel has ZERO
//      coherence machinery (plain stores/atomics, kernel boundary = coherence);
//      select kernel keeps the R3 gh-histogram win (no pass over cand to build
//      the hist) and the R11 MLP-filter win.

// ---------------- Kernel 1: streaming pass ----------------
__global__ __launch_bounds__(BT) void fused_stream(const float* __restrict__ logits,
                                                   unsigned int* __restrict__ cnt,
                                                   unsigned int* __restrict__ gh,
                                                   uint2* __restrict__ cand,
                                                   int cap) {
    __shared__ unsigned int lh[Cn * NBINS];   // 16.4 KB per-class local radix hist
    __shared__ unsigned int lcut[Cn], cls_cnt[Cn], cls_base[Cn], cls_pos[Cn];
    const int b = blockIdx.y;
    const int t = threadIdx.x;
    const int lane = t & 63;
    for (int j = t; j < Cn * NBINS; j += BT) lh[j] = 0u;
    if (t < Cn) { lcut[t] = 0u; cls_cnt[t] = 0u; cls_pos[t] = 0u; }
    __syncthreads();

    // phase 1: stream voxels (float4 x 4 class streams); results stay in registers
    const float* base = logits + (size_t)b * Cn * Sn;
    const float4* s0 = (const float4*)base;
    const float4* s1 = (const float4*)(base + Sn);
    const float4* s2 = (const float4*)(base + 2 * Sn);
    const float4* s3 = (const float4*)(base + 3 * Sn);
    const int qs = blockIdx.x * (PB / 4);
    unsigned int pk[PB / BT];   // 8 packed results per thread
    #pragma unroll
    for (int it = 0; it < PB / 4 / BT; ++it) {   // 2 iterations
        int q = qs + it * BT + t;
        float4 v0 = s0[q], v1 = s1[q], v2 = s2[q], v3 = s3[q];
        const float* a0 = &v0.x; const float* a1 = &v1.x;
        const float* a2 = &v2.x; const float* a3 = &v3.x;
        #pragma unroll
        for (int k = 0; k < 4; ++k) {
            int cm; float p;
            softmax_argmax4(a0[k], a1[k], a2[k], a3[k], &cm, &p);
            unsigned int pv = 0u;
            if (p > THRf) {
                unsigned int off = __float_as_uint(p) - 0x3F000000u;  // 1..0x800000
                atomicAdd(&lh[cm * NBINS + (int)(off >> 13)], 1u);    // no-return ds_add
                pv = (off << 2) | (unsigned int)cm;                   // 26 bits, nonzero
            }
            pk[it * 4 + k] = pv;
        }
    }
    __syncthreads();

    // phase 2: wave w (w<4) computes local cutoff for class w (64 lanes x 17 bins).
    // Entries below the local cutoff have >=32 strictly-greater local entries ->
    // global rank >= 32 -> safe to drop. Union over blocks is a superset of top-32.
    // The break-time acc = count of entries in bins >= lcut = exact emit count.
    {
        const int wave = t >> 6;
        if (wave < Cn) {
            const unsigned int* h = &lh[wave * NBINS];
            const int lo = lane * 17;
            unsigned int cs = 0;
            #pragma unroll
            for (int k = 0; k < 17; ++k) {
                int bin = lo + k;
                if (bin < NBINS) cs += h[bin];
            }
            unsigned int S = cs;  // inclusive suffix sum over lanes [lane..63]
            #pragma unroll
            for (int off = 1; off < 64; off <<= 1) {
                unsigned int v = __shfl_down(S, off, 64);
                if (lane + off < 64) S += v;
            }
            unsigned int suf = S - cs;
            if (S >= NPTS && suf < NPTS) {   // exactly one lane (when total >= 32)
                unsigned int acc = suf;
                int hi = min(lo + 16, NBINS - 1);
                for (int bin = hi; bin >= lo; --bin) {
                    acc += h[bin];
                    if (acc >= NPTS) {
                        lcut[wave] = (unsigned int)bin;
                        cls_cnt[wave] = acc;
                        break;
                    }
                }
            }
            if (lane == 0 && S < NPTS) cls_cnt[wave] = S;  // total<32: lcut=0, emit all
        }
    }
    __syncthreads();

    // phase 2.5: publish surviving bins (bin >= lcut, nonzero) into the global
    // per-(b,c) histogram == exactly the histogram of all emitted candidates.
    // Plain atomicAdd (device-scope by default); ~35 per class per block.
    {
        const int wave = t >> 6;
        if (wave < Cn) {
            const unsigned int* h = &lh[wave * NBINS];
            unsigned int* g = gh + (size_t)(b * Cn + wave) * NBINS;
            for (int bin = (int)lcut[wave] + lane; bin < NBINS; bin += 64) {
                unsigned int v = h[bin];
                if (v) atomicAdd(&g[bin], v);
            }
        }
    }
    // reservation: one global atomic per (block, class)
    if (t < Cn && cls_cnt[t] > 0)
        cls_base[t] = atomicAdd(&cnt[b * Cn + t], cls_cnt[t]);
    __syncthreads();

    // phase 3: emit survivors straight from registers (~130/block total).
    // Plain stores: the kernel boundary makes them visible to the select kernel.
    #pragma unroll
    for (int j = 0; j < PB / BT; ++j) {
        unsigned int pv = pk[j];
        if (pv != 0u) {
            unsigned int cm = pv & 3u;
            if ((pv >> 15) >= lcut[cm]) {   // pv>>15 == p_off>>13 == bin
                unsigned int pos = cls_base[cm] + atomicAdd(&cls_pos[cm], 1u);
                if (pos < (unsigned int)cap) {
                    int it = j >> 2, k = j & 3;
                    unsigned int idx = (unsigned int)((qs + it * BT + t) * 4 + k);
                    cand[(size_t)(b * Cn + cm) * cap + pos] =
                        make_uint2(0x3F000000u + (pv >> 2), idx);
                }
            }
        }
    }
}

// ---------------- Kernel 2: per-(b,c) exact selection + emit ----------------
// One block per (b,c). gh is already the complete candidate histogram, so this
// kernel does: exact cutoff scan -> ONE branch-free MLP filter pass over cand ->
// O(m^2) exact rank (m ~ 80) -> cross-class compaction by the last finisher of
// each batch (R0-proven 8-block threadfence pattern).
__global__ __launch_bounds__(BT2) void select_emit(const unsigned int* __restrict__ cnt,
                                                   const unsigned int* __restrict__ gh,
                                                   const uint2* __restrict__ cand,
                                                   int cap,
                                                   unsigned int* __restrict__ done,
                                                   unsigned int* __restrict__ validn,
                                                   uint2* __restrict__ topk,
                                                   int* __restrict__ out) {
    __shared__ unsigned int lh[NBINS];        // 4.1 KB this class's global hist
    __shared__ uint2 fbuf[FB];                // 8.2 KB survivors
    __shared__ unsigned int s_T, s_m, s_old;
    __shared__ int pre[Cn + 1];
    const int bc = blockIdx.x, t = threadIdx.x;
    const int b = bc >> 2;
    const int lane = t & 63;

    for (int j = t; j < NBINS; j += BT2) lh[j] = gh[(size_t)bc * NBINS + j];
    if (t == 0) { s_T = 0u; s_m = 0u; }
    __syncthreads();
    const int n = min((int)cnt[bc], cap);

    // exact global cutoff: wave 0 scans the 1025 bins
    if (t < 64) {
        const int lo = lane * 17;
        unsigned int cs = 0;
        #pragma unroll
        for (int k = 0; k < 17; ++k) {
            int bin = lo + k;
            if (bin < NBINS) cs += lh[bin];
        }
        unsigned int S = cs;
        #pragma unroll
        for (int off = 1; off < 64; off <<= 1) {
            unsigned int v = __shfl_down(S, off, 64);
            if (lane + off < 64) S += v;
        }
        unsigned int suf = S - cs;
        if (S >= NPTS && suf < NPTS) {
            unsigned int acc = suf;
            int hi = min(lo + 16, NBINS - 1);
            for (int bin = hi; bin >= lo; --bin) {
                acc += lh[bin];
                if (acc >= NPTS) { s_T = (unsigned int)bin; break; }
            }
        }
        // S < NPTS: s_T stays 0 -> keep everything
    }
    __syncthreads();
    const unsigned int T = s_T;

    // single filtered pass, branch-free 8-deep load batches (true MLP)
    {
        const uint2* src = cand + (size_t)bc * cap;
        for (int j0 = t; j0 < n; j0 += BT2 * 8) {
            uint2 e[8];
            #pragma unroll
            for (int k = 0; k < 8; ++k) {
                int j = j0 + k * BT2;
                e[k] = src[j < n ? j : (n > 0 ? n - 1 : 0)];   // clamped: always issues
            }
            #pragma unroll
            for (int k = 0; k < 8; ++k) {
                int j = j0 + k * BT2;
                if (j < n && (unsigned int)bin_of_bits(e[k].x) >= T) {
                    unsigned int pos = atomicAdd(&s_m, 1u);
                    if (pos < FB) fbuf[pos] = e[k];
                }
            }
        }
    }
    __syncthreads();

    // exact rank with jax tie-break (higher prob first; equal prob -> lower idx
    // first); ranks distinct (idx unique per class). ~80 survivors.
    const int m = min((int)s_m, FB);
    const int vn = min(n, NPTS);
    if (t == 0) validn[bc] = (unsigned int)vn;
    for (int i = t; i < m; i += BT2) {
        uint2 e = fbuf[i];
        int rank = 0;
        for (int j = 0; j < m; ++j) {
            uint2 o = fbuf[j];
            rank += (int)((o.x > e.x) || (o.x == e.x && o.y < e.y));
        }
        if (rank < vn) topk[bc * NPTS + rank] = e;
    }

    // epilogue: last finishing block of this batch emits (8 blocks total pay the
    // fence -- the R0-proven pattern).
    __threadfence();
    __syncthreads();
    if (t == 0) s_old = atomicAdd(&done[b], 1u);
    __syncthreads();
    if (s_old != 3u) return;
    __threadfence();   // acquire: see the other 3 classes' topk/validn

    if (t == 0) {
        int acc = 0;
        for (int oc = 0; oc < Cn; ++oc) {
            pre[oc] = acc;
            acc += (int)validn[b * Cn + ((oc + 1) & 3)];   // class order [1,2,3,0]
        }
        pre[Cn] = acc;
    }
    __syncthreads();

    if (t < Cn * NPTS) {   // 128 output slots for batch b
        const int j = t;
        int label = -1, z = 0, y = 0, x = 0;
        if (j < pre[Cn]) {
            int oc = 0;
            while (j >= pre[oc + 1]) ++oc;
            int c = (oc + 1) & 3;
            int r = j - pre[oc];
            uint2 e = topk[(b * Cn + c) * NPTS + r];
            int idx = (int)e.y;
            z = idx >> 14;          // idx / (128*128)
            y = (idx >> 7) & 127;   // (idx / 128) % 128
            x = idx & 127;          // idx % 128
            label = c;
        }
        int* coords = out;                       // 2*128*3 = 768 ints
        int* labels = out + Bn * Cn * NPTS * 3;  // then 2*128 = 256 ints
        int bo = b * Cn * NPTS + j;
        coords[bo * 3 + 0] = z;
        coords[bo * 3 + 1] = y;
        coords[bo * 3 + 2] = x;
        labels[bo] = label;
    }
}

extern "C" void kernel_launch(void* const* d_in, const int* in_sizes, int n_in,
                              void* d_out, int out_size, void* d_ws, size_t ws_size,
                              hipStream_t stream) {
    const float* logits = (const float*)d_in[0];
    int* out = (int*)d_out;

    // Workspace layout (zeroed region first, contiguous: cnt, done, gh)
    unsigned int* cnt = (unsigned int*)d_ws;             // 8 u32    @0
    unsigned int* done = cnt + Bn * Cn;                  // 2 u32    @32
    unsigned int* gh = done + Bn;                        // 8*1025   @40
    unsigned int* validn = gh + Bn * Cn * NBINS;         // 8 u32    @32840
    uint2* topk = (uint2*)(validn + Bn * Cn);            // 256 uint2 @32872 (8-aligned)
    uint2* cand = topk + Bn * Cn * NPTS;                 // @34920
    size_t fixed = (size_t)((char*)cand - (char*)d_ws);
    int cap = (int)((ws_size - fixed) / (Bn * Cn * sizeof(uint2)));
    if (cap > (1 << 18)) cap = 1 << 18;   // 256k entries/bc >> the ~18k expected
    if (cap < 4096) cap = 4096;

    // Zero cnt + done + gh (contiguous, ~33 KB; workspace is harness-poisoned)
    hipMemsetAsync(cnt, 0, (size_t)(Bn * Cn + Bn + Bn * Cn * NBINS) * sizeof(unsigned int),
                   stream);

    dim3 grid(Sn / PB, Bn);   // (512, 2) = 1024 blocks, co-resident at 4 blk/CU
    fused_stream<<<grid, BT, 0, stream>>>(logits, cnt, gh, cand, cap);
    select_emit<<<Bn * Cn, BT2, 0, stream>>>(cnt, gh, cand, cap, done, validn, topk, out);
}